// Round 2
// baseline (973.266 us; speedup 1.0000x reference)
//
#include <hip/hip_runtime.h>
#include <stdint.h>

// MultiHeadSlotAttention on MI355X (gfx950).
// Identity: dots = (SCALE*q@Wk_h^T).x_ln + SCALE*q.bk ; updates = ((sum_j p*x_ln + EPS*xsum)/S)@Wv + bv
// -> K and V are never materialized. Per iteration: one MFMA attention pass over x_ln
// (re-LN'd on the fly), then an MFMA update kernel (A-reduce + GRU + MLP + next-iter q prep).
// All bf16 handled as `short` storage + manual RNE convert (no __bf16 API dependency).

#define NSLOT 8
#define R32   32   // NUM_SLOTS*N_HEADS
#define SEQN  4096

constexpr float EPSA    = 1e-8f;
constexpr float LNEPS   = 1e-5f;
constexpr float SCALE_F = 0.125f;   // 64^-0.5

typedef short s16x8 __attribute__((ext_vector_type(8)));
typedef short s16x4 __attribute__((ext_vector_type(4)));
typedef float f32x4 __attribute__((ext_vector_type(4)));

__device__ __forceinline__ short f2bf(float f) {
  uint32_t u = __float_as_uint(f);
  uint32_t r = (u + 0x7FFFu + ((u >> 16) & 1u)) >> 16;
  return (short)r;
}
__device__ __forceinline__ s16x8 cvt8(const float* p) {  // p must be 16B-aligned
  f32x4 a = *(const f32x4*)p;
  f32x4 b = *(const f32x4*)(p + 4);
  s16x8 r;
  r[0]=f2bf(a[0]); r[1]=f2bf(a[1]); r[2]=f2bf(a[2]); r[3]=f2bf(a[3]);
  r[4]=f2bf(b[0]); r[5]=f2bf(b[1]); r[6]=f2bf(b[2]); r[7]=f2bf(b[3]);
  return r;
}

// ---------------------------------------------------------------------------
// w_cast: fp32 -> bf16 straight copies (W_ih, W_hh, Wk). 448 blocks x 256.
// ---------------------------------------------------------------------------
__global__ __launch_bounds__(256) void w_cast(
    const float* __restrict__ W_ih, const float* __restrict__ W_hh,
    const float* __restrict__ Wk,
    short* __restrict__ WihB, short* __restrict__ WhhB, short* __restrict__ WkB)
{
  int idx4 = blockIdx.x*256 + threadIdx.x;   // float4 index
  const float* src; short* dst; int off;
  if (idx4 < 49152)        { src = W_ih; dst = WihB; off = idx4; }
  else if (idx4 < 98304)   { src = W_hh; dst = WhhB; off = idx4 - 49152; }
  else                     { src = Wk;   dst = WkB;  off = idx4 - 98304; }
  f32x4 v = *(const f32x4*)(src + 4*(size_t)off);
  s16x4 o; o[0]=f2bf(v[0]); o[1]=f2bf(v[1]); o[2]=f2bf(v[2]); o[3]=f2bf(v[3]);
  *(s16x4*)(dst + 4*(size_t)off) = o;
}

// ---------------------------------------------------------------------------
// w_trans: fp32 [R][C] -> bf16 [C][R] (Wv, W1, W2, Wq). 96 blocks x 256.
// ---------------------------------------------------------------------------
__global__ __launch_bounds__(256) void w_trans(
    const float* __restrict__ Wv, const float* __restrict__ W1,
    const float* __restrict__ W2, const float* __restrict__ Wq,
    short* __restrict__ WvT, short* __restrict__ W1T,
    short* __restrict__ W2T, short* __restrict__ WqT)
{
  __shared__ float tile[64][65];
  int bid = blockIdx.x, t = threadIdx.x;
  const float* src; short* dst; int R, C, tr, tc;
  if (bid < 16)      { src = Wv; dst = WvT; R = 256; C = 256; int q = bid;      tr = q >> 2; tc = q & 3; }
  else if (bid < 48) { src = W1; dst = W1T; R = 256; C = 512; int q = bid - 16; tr = q >> 3; tc = q & 7; }
  else if (bid < 80) { src = W2; dst = W2T; R = 512; C = 256; int q = bid - 48; tr = q >> 2; tc = q & 3; }
  else               { src = Wq; dst = WqT; R = 256; C = 256; int q = bid - 80; tr = q >> 2; tc = q & 3; }
  int r0 = tr*64, c0 = tc*64;
  for (int p = t; p < 4096; p += 256) {
    int rr = p >> 6, cc = p & 63;
    tile[rr][cc] = src[(size_t)(r0 + rr)*C + c0 + cc];
  }
  __syncthreads();
  for (int p = t; p < 4096; p += 256) {
    int cc = p >> 6, rr = p & 63;
    dst[(size_t)(c0 + cc)*R + r0 + rr] = f2bf(tile[rr][cc]);
  }
}

// ---------------------------------------------------------------------------
// s0_prep: per (b,slot): copy slots_init->slots_cur, LN_s, q = s@Wq+bq,
// qk~[h][c] = SCALE*sum_d q[h*64+d]*Wk[c][h*64+d] (bf16), qb = SCALE*q.bk_h
// ---------------------------------------------------------------------------
__global__ __launch_bounds__(256) void s0_prep(
    const float* __restrict__ slots_init,
    const float* __restrict__ ln_s_g, const float* __restrict__ ln_s_b,
    const float* __restrict__ Wq, const float* __restrict__ bq,
    const float* __restrict__ Wk, const float* __restrict__ bk,
    float* __restrict__ slots_cur, short* __restrict__ qk, float* __restrict__ qb)
{
  __shared__ float red[8];
  __shared__ float sln[256], qv[256];
  int b = blockIdx.x >> 3, i = blockIdx.x & 7;
  int t = threadIdx.x;
  int row_base = (b*NSLOT + i)*256;
  float si = slots_init[row_base + t];
  slots_cur[row_base + t] = si;
  float s = si, s2 = si*si;
  #pragma unroll
  for (int m = 1; m < 64; m <<= 1) { s += __shfl_xor(s, m); s2 += __shfl_xor(s2, m); }
  if ((t & 63) == 0) { red[t >> 6] = s; red[4 + (t >> 6)] = s2; }
  __syncthreads();
  s  = red[0] + red[1] + red[2] + red[3];
  s2 = red[4] + red[5] + red[6] + red[7];
  float mu = s*(1.f/256.f), var = s2*(1.f/256.f) - mu*mu;
  float rs = 1.f/sqrtf(var + LNEPS);
  sln[t] = (si - mu)*rs*ln_s_g[t] + ln_s_b[t];
  __syncthreads();
  float acc = bq[t];
  for (int c = 0; c < 256; ++c) acc += sln[c]*Wq[(c << 8) + t];
  qv[t] = acc;
  __syncthreads();
  float a0 = 0.f, a1 = 0.f, a2 = 0.f, a3 = 0.f;
  const float* wr = Wk + ((size_t)t << 8);
  for (int d = 0; d < 64; ++d) {
    a0 += qv[d]*wr[d];         a1 += qv[64+d]*wr[64+d];
    a2 += qv[128+d]*wr[128+d]; a3 += qv[192+d]*wr[192+d];
  }
  short* qrow = qk + (size_t)(b*R32 + i*4)*256 + t;
  qrow[0]   = f2bf(SCALE_F*a0);
  qrow[256] = f2bf(SCALE_F*a1);
  qrow[512] = f2bf(SCALE_F*a2);
  qrow[768] = f2bf(SCALE_F*a3);
  int h = t >> 6, d2 = t & 63;
  float pv = qv[h*64 + d2]*bk[h*64 + d2];
  #pragma unroll
  for (int m = 1; m < 64; m <<= 1) pv += __shfl_xor(pv, m);
  if (d2 == 0) qb[b*R32 + i*4 + h] = SCALE_F*pv;
}

// ---------------------------------------------------------------------------
// attn: grid 512 = (b, chunk of 256 j). 4 waves, 4 steps of 64 j each.
// LDS layout (shorts for x tiles), 80000 B total.
// ---------------------------------------------------------------------------
#define XSTR 264
#define TSTR 72
#define PSTR 72
#define OFF_XT   (64*XSTR*2)
#define OFF_PS   (OFF_XT + 256*TSTR*2)
#define OFF_PSUM (OFF_PS + 32*PSTR*2)
#define OFF_XSUM (OFF_PSUM + 4*32*4)
#define OFF_QB   (OFF_XSUM + 4*256*4)
#define SMEM_BYTES (OFF_QB + 32*4)   // 80000

__global__ __launch_bounds__(256, 2) void attn_kernel(
    const float* __restrict__ inp,
    const float* __restrict__ ln_f_g, const float* __restrict__ ln_f_b,
    const short* __restrict__ qk, const float* __restrict__ qb,
    float* __restrict__ A_part, float* __restrict__ psum_part,
    float* __restrict__ xsum_part, int write_xsum)
{
  extern __shared__ char smem[];
  short* xs       = (short*)smem;               // [64][XSTR]
  short* xt       = (short*)(smem + OFF_XT);    // [256][TSTR] (x transposed)
  short* ps       = (short*)(smem + OFF_PS);    // [32][PSTR]
  float* psum_lds = (float*)(smem + OFF_PSUM);  // [4][32]
  float* xsum_lds = (float*)(smem + OFF_XSUM);  // [4][256]
  float* qb_lds   = (float*)(smem + OFF_QB);    // [32]

  int tid = threadIdx.x;
  int w = tid >> 6, lane = tid & 63;
  int g = lane >> 4, lj = lane & 15;
  int b = blockIdx.x >> 4, chunk = blockIdx.x & 15;

  float gc[4], bc[4];
  #pragma unroll
  for (int q = 0; q < 4; ++q) { gc[q] = ln_f_g[lane + 64*q]; bc[q] = ln_f_b[lane + 64*q]; }

  if (tid < 32) qb_lds[tid] = qb[b*R32 + tid];

  s16x8 qkf[2][8];
  #pragma unroll
  for (int mt = 0; mt < 2; ++mt)
    #pragma unroll
    for (int ks = 0; ks < 8; ++ks)
      qkf[mt][ks] = *(const s16x8*)(qk + ((size_t)(b*R32 + mt*16 + lj) << 8) + ks*32 + g*8);
  __syncthreads();

  float qb0[4], qb1[4];
  #pragma unroll
  for (int r = 0; r < 4; ++r) { qb0[r] = qb_lds[4*g + r]; qb1[r] = qb_lds[16 + 4*g + r]; }

  f32x4 zero4 = {0.f, 0.f, 0.f, 0.f};
  f32x4 accD[2][4];
  #pragma unroll
  for (int mt = 0; mt < 2; ++mt)
    #pragma unroll
    for (int nt = 0; nt < 4; ++nt) accD[mt][nt] = zero4;
  float psum_acc[8] = {0.f,0.f,0.f,0.f,0.f,0.f,0.f,0.f};
  float xsum_acc[4] = {0.f,0.f,0.f,0.f};

  for (int step = 0; step < 4; ++step) {
    int jbase = chunk*256 + step*64;
    const float* rowp = inp + (((size_t)b*SEQN + jbase + w*16) << 8);
    short tq[4][4];
    #pragma unroll
    for (int rr = 0; rr < 16; ++rr) {
      const float* rp = rowp + ((size_t)rr << 8);
      float v0 = rp[lane], v1 = rp[lane+64], v2 = rp[lane+128], v3 = rp[lane+192];
      float s  = v0 + v1 + v2 + v3;
      float s2 = v0*v0 + v1*v1 + v2*v2 + v3*v3;
      #pragma unroll
      for (int m = 1; m < 64; m <<= 1) { s += __shfl_xor(s, m); s2 += __shfl_xor(s2, m); }
      float mu = s*(1.f/256.f);
      float var = s2*(1.f/256.f) - mu*mu;
      float rs = 1.f/sqrtf(var + LNEPS);
      int jrow = w*16 + rr;
      float vv[4] = {v0, v1, v2, v3};
      #pragma unroll
      for (int q = 0; q < 4; ++q) {
        float xl = (vv[q] - mu)*rs*gc[q] + bc[q];
        xsum_acc[q] += xl;
        short hv = f2bf(xl);
        xs[jrow*XSTR + lane + 64*q] = hv;
        tq[q][rr & 3] = hv;
      }
      if ((rr & 3) == 3) {
        #pragma unroll
        for (int q = 0; q < 4; ++q) {
          s16x4 pk = { tq[q][0], tq[q][1], tq[q][2], tq[q][3] };
          *(s16x4*)(xt + (lane + 64*q)*TSTR + w*16 + (rr - 3)) = pk;
        }
      }
    }
    // GEMM1: dots[32][16] on this wave's own 16 j (same-wave LDS RAW is in-order)
    f32x4 d0 = zero4, d1 = zero4;
    #pragma unroll
    for (int ks = 0; ks < 8; ++ks) {
      s16x8 bx = *(const s16x8*)(xs + (w*16 + lj)*XSTR + ks*32 + g*8);
      d0 = __builtin_amdgcn_mfma_f32_16x16x32_bf16(qkf[0][ks], bx, d0, 0, 0, 0);
      d1 = __builtin_amdgcn_mfma_f32_16x16x32_bf16(qkf[1][ks], bx, d1, 0, 0, 0);
    }
    // softmax over the 32 (slot,head) rows per column j
    {
      float m0 = -1e30f;
      #pragma unroll
      for (int r = 0; r < 4; ++r) {
        m0 = fmaxf(m0, d0[r] + qb0[r]);
        m0 = fmaxf(m0, d1[r] + qb1[r]);
      }
      m0 = fmaxf(m0, __shfl_xor(m0, 16));
      m0 = fmaxf(m0, __shfl_xor(m0, 32));
      float e0[4], e1[4], ssum = 0.f;
      #pragma unroll
      for (int r = 0; r < 4; ++r) {
        e0[r] = __expf(d0[r] + qb0[r] - m0);
        e1[r] = __expf(d1[r] + qb1[r] - m0);
        ssum += e0[r] + e1[r];
      }
      ssum += __shfl_xor(ssum, 16);
      ssum += __shfl_xor(ssum, 32);
      float inv = 1.f/ssum;
      int jl = w*16 + lj;
      #pragma unroll
      for (int r = 0; r < 4; ++r) {
        float sm0 = e0[r]*inv, sm1 = e1[r]*inv;
        psum_acc[r]     += sm0;
        psum_acc[4 + r] += sm1;
        ps[(4*g + r)*PSTR + jl]      = f2bf(sm0);
        ps[(16 + 4*g + r)*PSTR + jl] = f2bf(sm1);
      }
    }
    __syncthreads();   // ps + xt complete for all waves
    // GEMM2: A_p[32][wave's 64 c] += p[32][64] * xT
    #pragma unroll
    for (int ks = 0; ks < 2; ++ks) {
      s16x8 pa0 = *(const s16x8*)(ps + lj*PSTR + ks*32 + g*8);
      s16x8 pa1 = *(const s16x8*)(ps + (16 + lj)*PSTR + ks*32 + g*8);
      #pragma unroll
      for (int nt = 0; nt < 4; ++nt) {
        s16x8 bxt = *(const s16x8*)(xt + (w*64 + nt*16 + lj)*TSTR + ks*32 + g*8);
        accD[0][nt] = __builtin_amdgcn_mfma_f32_16x16x32_bf16(pa0, bxt, accD[0][nt], 0, 0, 0);
        accD[1][nt] = __builtin_amdgcn_mfma_f32_16x16x32_bf16(pa1, bxt, accD[1][nt], 0, 0, 0);
      }
    }
    __syncthreads();   // before next step overwrites LDS
  }

  {
    float* ap = A_part + ((size_t)(b*16 + chunk) << 13);
    #pragma unroll
    for (int mt = 0; mt < 2; ++mt)
      #pragma unroll
      for (int nt = 0; nt < 4; ++nt)
        #pragma unroll
        for (int r = 0; r < 4; ++r)
          ap[(mt*16 + 4*g + r)*256 + w*64 + nt*16 + lj] = accD[mt][nt][r];
  }
  #pragma unroll
  for (int r = 0; r < 8; ++r)
    #pragma unroll
    for (int m = 1; m < 16; m <<= 1) psum_acc[r] += __shfl_xor(psum_acc[r], m);
  if (lj == 0) {
    #pragma unroll
    for (int r = 0; r < 4; ++r) {
      psum_lds[w*32 + 4*g + r]      = psum_acc[r];
      psum_lds[w*32 + 16 + 4*g + r] = psum_acc[4 + r];
    }
  }
  #pragma unroll
  for (int q = 0; q < 4; ++q) xsum_lds[w*256 + lane + 64*q] = xsum_acc[q];
  __syncthreads();
  if (tid < 32) {
    float sv = psum_lds[tid] + psum_lds[32+tid] + psum_lds[64+tid] + psum_lds[96+tid];
    psum_part[(b*16 + chunk)*32 + tid] = sv;
  }
  if (write_xsum) {
    float sv = xsum_lds[tid] + xsum_lds[256+tid] + xsum_lds[512+tid] + xsum_lds[768+tid];
    xsum_part[((b*16 + chunk) << 8) + tid] = sv;
  }
}

// ---------------------------------------------------------------------------
// s3_update: grid 32 (one per batch b), 256 threads (4 waves), MFMA stages.
// M=8 slot rows per block; wave w = head (stage 1/8) or N-quarter owner.
// ---------------------------------------------------------------------------
#define AST 260
#define WST 520
#define S3_AF   0
#define S3_HP   (S3_AF + 32*AST)
#define S3_UU   (S3_HP + 8*AST)
#define S3_RZ   (S3_UU + 8*AST)
#define S3_INN  (S3_RZ + 8*WST)
#define S3_HNN  (S3_INN + 8*AST)
#define S3_SNL  (S3_HNN + 8*AST)
#define S3_LNS  (S3_SNL + 8*AST)
#define S3_HH   (S3_LNS + 8*AST)
#define S3_QV   (S3_HH + 8*WST)
#define S3_XSV  (S3_QV + 8*AST)
#define S3_SR   (S3_XSV + 256)
#define S3_BYTES ((S3_SR + 32)*4)   // 125952

__global__ __launch_bounds__(256, 1) void s3_update(
    const float* __restrict__ A_part, const float* __restrict__ psum_part,
    const float* __restrict__ xsum_part,
    const short* __restrict__ WihB, const short* __restrict__ WhhB,
    const short* __restrict__ WkB,  const short* __restrict__ WvT,
    const short* __restrict__ W1T,  const short* __restrict__ W2T,
    const short* __restrict__ WqT,
    const float* __restrict__ bv,   const float* __restrict__ b_ih,
    const float* __restrict__ b_hh,
    const float* __restrict__ ln_ff_g, const float* __restrict__ ln_ff_b,
    const float* __restrict__ b1,   const float* __restrict__ b2,
    const float* __restrict__ ln_s_g, const float* __restrict__ ln_s_b,
    const float* __restrict__ bq,   const float* __restrict__ bk,
    float* __restrict__ slots_cur, short* __restrict__ qk,
    float* __restrict__ qb, float* __restrict__ out)
{
  extern __shared__ float sm[];
  int b = blockIdx.x, t = threadIdx.x;
  int w = t >> 6, lane = t & 63, g = lane >> 4, lj = lane & 15;
  int ar = lj & 7;   // A-source slot row (rows 8..15 duplicate; D rows 8..15 unused)

  // ---- stage 0: xsv, Sr, hp, Af ----
  {
    float x = 0.f;
    for (int ch = 0; ch < 16; ++ch) x += xsum_part[((b*16 + ch) << 8) + t];
    sm[S3_XSV + t] = x;
  }
  if (t < 32) {
    float p = 0.f;
    for (int ch = 0; ch < 16; ++ch) p += psum_part[(b*16 + ch)*32 + t];
    sm[S3_SR + t] = p + 4096.f*EPSA;
  }
  for (int idx = t; idx < 2048; idx += 256)
    sm[S3_HP + (idx >> 8)*AST + (idx & 255)] = slots_cur[b*2048 + idx];
  __syncthreads();
  for (int idx = t; idx < 8192; idx += 256) {
    int r = idx >> 8, c = idx & 255;
    float a = 0.f;
    for (int ch = 0; ch < 16; ++ch)
      a += A_part[(size_t)((b*16 + ch)*32 + r)*256 + c];
    sm[S3_AF + r*AST + c] = (a + EPSA*sm[S3_XSV + c]) / sm[S3_SR + r];
  }
  __syncthreads();

  // ---- stage 1: uu = Af(head rows) @ WvT + bv ; wave w = head ----
  {
    s16x8 af[8];
    const float* ab = sm + S3_AF + (ar*4 + w)*AST;
    #pragma unroll
    for (int ks = 0; ks < 8; ++ks) af[ks] = cvt8(ab + ks*32 + g*8);
    #pragma unroll
    for (int nt = 0; nt < 4; ++nt) {
      int n = w*64 + nt*16 + lj;
      f32x4 acc = {0.f,0.f,0.f,0.f};
      #pragma unroll
      for (int ks = 0; ks < 8; ++ks) {
        s16x8 bf = *(const s16x8*)(WvT + ((size_t)n << 8) + ks*32 + g*8);
        acc = __builtin_amdgcn_mfma_f32_16x16x32_bf16(af[ks], bf, acc, 0, 0, 0);
      }
      if (g < 2) {
        float bvn = bv[n];
        #pragma unroll
        for (int r = 0; r < 4; ++r) sm[S3_UU + (4*g + r)*AST + n] = acc[r] + bvn;
      }
    }
  }
  __syncthreads();

  // ---- stage 2: GRU gate matmuls ----
  {
    s16x8 uf[8], hf[8];
    const float* ub = sm + S3_UU + ar*AST;
    const float* hb = sm + S3_HP + ar*AST;
    #pragma unroll
    for (int ks = 0; ks < 8; ++ks) { uf[ks] = cvt8(ub + ks*32 + g*8); hf[ks] = cvt8(hb + ks*32 + g*8); }
    // r,z: fused accumulate gi+gh (N = 0..511)
    #pragma unroll
    for (int nt = 0; nt < 8; ++nt) {
      int n = w*128 + nt*16 + lj;
      f32x4 acc = {0.f,0.f,0.f,0.f};
      #pragma unroll
      for (int ks = 0; ks < 8; ++ks)
        acc = __builtin_amdgcn_mfma_f32_16x16x32_bf16(uf[ks], *(const s16x8*)(WihB + (size_t)n*256 + ks*32 + g*8), acc, 0, 0, 0);
      #pragma unroll
      for (int ks = 0; ks < 8; ++ks)
        acc = __builtin_amdgcn_mfma_f32_16x16x32_bf16(hf[ks], *(const s16x8*)(WhhB + (size_t)n*256 + ks*32 + g*8), acc, 0, 0, 0);
      if (g < 2) {
        float bb = b_ih[n] + b_hh[n];
        #pragma unroll
        for (int r = 0; r < 4; ++r) sm[S3_RZ + (4*g + r)*WST + n] = acc[r] + bb;
      }
    }
    // inn / hnn separate (rows 512..767)
    #pragma unroll
    for (int nt = 0; nt < 4; ++nt) {
      int n = w*64 + nt*16 + lj;
      f32x4 ai = {0.f,0.f,0.f,0.f}, ah = {0.f,0.f,0.f,0.f};
      #pragma unroll
      for (int ks = 0; ks < 8; ++ks) {
        ai = __builtin_amdgcn_mfma_f32_16x16x32_bf16(uf[ks], *(const s16x8*)(WihB + (size_t)(512 + n)*256 + ks*32 + g*8), ai, 0, 0, 0);
        ah = __builtin_amdgcn_mfma_f32_16x16x32_bf16(hf[ks], *(const s16x8*)(WhhB + (size_t)(512 + n)*256 + ks*32 + g*8), ah, 0, 0, 0);
      }
      if (g < 2) {
        float bi2 = b_ih[512 + n], bh2 = b_hh[512 + n];
        #pragma unroll
        for (int r = 0; r < 4; ++r) {
          sm[S3_INN + (4*g + r)*AST + n] = ai[r] + bi2;
          sm[S3_HNN + (4*g + r)*AST + n] = ah[r] + bh2;
        }
      }
    }
  }
  __syncthreads();

  // ---- stage 3: gates + new slots (pre-MLP) ----
  for (int idx = t; idx < 2048; idx += 256) {
    int s = idx >> 8, c = idx & 255;
    float rg = 1.f/(1.f + __expf(-sm[S3_RZ + s*WST + c]));
    float zg = 1.f/(1.f + __expf(-sm[S3_RZ + s*WST + 256 + c]));
    float ng = tanhf(sm[S3_INN + s*AST + c] + rg*sm[S3_HNN + s*AST + c]);
    sm[S3_SNL + s*AST + c] = (1.f - zg)*ng + zg*sm[S3_HP + s*AST + c];
  }
  __syncthreads();

  // ---- stage 4: LN_ff(snl) -> lns ----
  {
    int s = t >> 5, lg2 = t & 31;
    float s1 = 0.f, s2 = 0.f;
    for (int c = lg2; c < 256; c += 32) { float v = sm[S3_SNL + s*AST + c]; s1 += v; s2 += v*v; }
    #pragma unroll
    for (int m = 1; m < 32; m <<= 1) { s1 += __shfl_xor(s1, m); s2 += __shfl_xor(s2, m); }
    float mu = s1*(1.f/256.f), var = s2*(1.f/256.f) - mu*mu;
    float rs = 1.f/sqrtf(var + LNEPS);
    for (int c = lg2; c < 256; c += 32)
      sm[S3_LNS + s*AST + c] = (sm[S3_SNL + s*AST + c] - mu)*rs*ln_ff_g[c] + ln_ff_b[c];
  }
  __syncthreads();

  // ---- stage 5: MLP1 = relu(lns @ W1T + b1) -> hh ----
  {
    s16x8 af[8];
    const float* ab = sm + S3_LNS + ar*AST;
    #pragma unroll
    for (int ks = 0; ks < 8; ++ks) af[ks] = cvt8(ab + ks*32 + g*8);
    #pragma unroll
    for (int nt = 0; nt < 8; ++nt) {
      int n = w*128 + nt*16 + lj;
      f32x4 acc = {0.f,0.f,0.f,0.f};
      #pragma unroll
      for (int ks = 0; ks < 8; ++ks)
        acc = __builtin_amdgcn_mfma_f32_16x16x32_bf16(af[ks], *(const s16x8*)(W1T + (size_t)n*256 + ks*32 + g*8), acc, 0, 0, 0);
      if (g < 2) {
        float b1n = b1[n];
        #pragma unroll
        for (int r = 0; r < 4; ++r) sm[S3_HH + (4*g + r)*WST + n] = fmaxf(acc[r] + b1n, 0.f);
      }
    }
  }
  __syncthreads();

  // ---- stage 6: MLP2 + residual -> final slots; write out/slots_cur ----
  {
    s16x8 af[16];
    const float* ab = sm + S3_HH + ar*WST;
    #pragma unroll
    for (int ks = 0; ks < 16; ++ks) af[ks] = cvt8(ab + ks*32 + g*8);
    #pragma unroll
    for (int nt = 0; nt < 4; ++nt) {
      int n = w*64 + nt*16 + lj;
      f32x4 acc = {0.f,0.f,0.f,0.f};
      #pragma unroll
      for (int ks = 0; ks < 16; ++ks)
        acc = __builtin_amdgcn_mfma_f32_16x16x32_bf16(af[ks], *(const s16x8*)(W2T + (size_t)n*512 + ks*32 + g*8), acc, 0, 0, 0);
      if (g < 2) {
        float b2n = b2[n];
        #pragma unroll
        for (int r = 0; r < 4; ++r) {
          int s = 4*g + r;
          float sf = sm[S3_SNL + s*AST + n] + acc[r] + b2n;
          sm[S3_SNL + s*AST + n] = sf;
          out[(b*8 + s)*256 + n] = sf;
          slots_cur[(b*8 + s)*256 + n] = sf;
        }
      }
    }
  }
  __syncthreads();

  // ---- stage 7: LN_s(final slots) -> lns ; qv = lns @ WqT + bq ----
  {
    int s = t >> 5, lg2 = t & 31;
    float s1 = 0.f, s2 = 0.f;
    for (int c = lg2; c < 256; c += 32) { float v = sm[S3_SNL + s*AST + c]; s1 += v; s2 += v*v; }
    #pragma unroll
    for (int m = 1; m < 32; m <<= 1) { s1 += __shfl_xor(s1, m); s2 += __shfl_xor(s2, m); }
    float mu = s1*(1.f/256.f), var = s2*(1.f/256.f) - mu*mu;
    float rs = 1.f/sqrtf(var + LNEPS);
    for (int c = lg2; c < 256; c += 32)
      sm[S3_LNS + s*AST + c] = (sm[S3_SNL + s*AST + c] - mu)*rs*ln_s_g[c] + ln_s_b[c];
  }
  __syncthreads();
  {
    s16x8 af[8];
    const float* ab = sm + S3_LNS + ar*AST;
    #pragma unroll
    for (int ks = 0; ks < 8; ++ks) af[ks] = cvt8(ab + ks*32 + g*8);
    #pragma unroll
    for (int nt = 0; nt < 4; ++nt) {
      int n = w*64 + nt*16 + lj;
      f32x4 acc = {0.f,0.f,0.f,0.f};
      #pragma unroll
      for (int ks = 0; ks < 8; ++ks)
        acc = __builtin_amdgcn_mfma_f32_16x16x32_bf16(af[ks], *(const s16x8*)(WqT + (size_t)n*256 + ks*32 + g*8), acc, 0, 0, 0);
      if (g < 2) {
        float bqn = bq[n];
        #pragma unroll
        for (int r = 0; r < 4; ++r) sm[S3_QV + (4*g + r)*AST + n] = acc[r] + bqn;
      }
    }
  }
  __syncthreads();

  // ---- stage 8: qk~ = SCALE * qv_head @ Wk_head^T (bf16 out) ; qb ----
  {
    s16x8 af2[2];
    const float* ab = sm + S3_QV + ar*AST + w*64;   // wave w = head
    af2[0] = cvt8(ab + g*8);
    af2[1] = cvt8(ab + 32 + g*8);
    #pragma unroll
    for (int nt = 0; nt < 16; ++nt) {
      int c = nt*16 + lj;
      f32x4 acc = {0.f,0.f,0.f,0.f};
      #pragma unroll
      for (int ks = 0; ks < 2; ++ks)
        acc = __builtin_amdgcn_mfma_f32_16x16x32_bf16(af2[ks], *(const s16x8*)(WkB + ((size_t)c << 8) + w*64 + ks*32 + g*8), acc, 0, 0, 0);
      if (g < 2) {
        #pragma unroll
        for (int r = 0; r < 4; ++r)
          qk[((size_t)b*R32 + (4*g + r)*4 + w)*256 + c] = f2bf(SCALE_F*acc[r]);
      }
    }
    int pr = t >> 3, dg = t & 7;
    int s = pr >> 2, h = pr & 3;
    float pv = 0.f;
    for (int d = dg*8; d < dg*8 + 8; ++d) pv += sm[S3_QV + s*AST + h*64 + d]*bk[h*64 + d];
    pv += __shfl_xor(pv, 1); pv += __shfl_xor(pv, 2); pv += __shfl_xor(pv, 4);
    if (dg == 0) qb[b*R32 + pr] = SCALE_F*pv;
  }
}

// ---------------------------------------------------------------------------
extern "C" void kernel_launch(void* const* d_in, const int* in_sizes, int n_in,
                              void* d_out, int out_size, void* d_ws, size_t ws_size,
                              hipStream_t stream) {
  (void)in_sizes; (void)n_in; (void)out_size; (void)ws_size;
  const float* inp        = (const float*)d_in[0];
  const float* slots_init = (const float*)d_in[1];
  const float* ln_f_g = (const float*)d_in[2];
  const float* ln_f_b = (const float*)d_in[3];
  const float* ln_s_g = (const float*)d_in[4];
  const float* ln_s_b = (const float*)d_in[5];
  const float* ln_ff_g = (const float*)d_in[6];
  const float* ln_ff_b = (const float*)d_in[7];
  const float* Wq = (const float*)d_in[8];
  const float* bq = (const float*)d_in[9];
  const float* Wk = (const float*)d_in[10];
  const float* bk = (const float*)d_in[11];
  const float* Wv = (const float*)d_in[12];
  const float* bv = (const float*)d_in[13];
  const float* W_ih = (const float*)d_in[14];
  const float* b_ih = (const float*)d_in[15];
  const float* W_hh = (const float*)d_in[16];
  const float* b_hh = (const float*)d_in[17];
  const float* W1 = (const float*)d_in[18];
  const float* b1 = (const float*)d_in[19];
  const float* W2 = (const float*)d_in[20];
  const float* b2 = (const float*)d_in[21];
  float* out = (float*)d_out;

  char* ws = (char*)d_ws;
  float* A_part    = (float*)(ws + 0);          // 16,777,216
  float* psum_part = (float*)(ws + 16777216);   // 65,536
  float* xsum_part = (float*)(ws + 16842752);   // 524,288
  short* qk        = (short*)(ws + 17367040);   // 524,288
  float* qbuf      = (float*)(ws + 17891328);   // 4,096
  float* slots_cur = (float*)(ws + 17895424);   // 262,144
  short* WihB      = (short*)(ws + 18157568);   // 393,216
  short* WhhB      = (short*)(ws + 18550784);   // 393,216
  short* WkB       = (short*)(ws + 18944000);   // 131,072
  short* WvT       = (short*)(ws + 19075072);   // 131,072
  short* W1T       = (short*)(ws + 19206144);   // 262,144
  short* W2T       = (short*)(ws + 19468288);   // 262,144
  short* WqT       = (short*)(ws + 19730432);   // 131,072  -> total 19,861,504 B

  hipFuncSetAttribute((const void*)attn_kernel,
                      hipFuncAttributeMaxDynamicSharedMemorySize, SMEM_BYTES);
  hipFuncSetAttribute((const void*)s3_update,
                      hipFuncAttributeMaxDynamicSharedMemorySize, S3_BYTES);

  w_cast<<<448, 256, 0, stream>>>(W_ih, W_hh, Wk, WihB, WhhB, WkB);
  w_trans<<<96, 256, 0, stream>>>(Wv, W1, W2, Wq, WvT, W1T, W2T, WqT);
  s0_prep<<<256, 256, 0, stream>>>(slots_init, ln_s_g, ln_s_b, Wq, bq, Wk, bk,
                                   slots_cur, qk, qbuf);
  for (int it = 0; it < 5; ++it) {
    attn_kernel<<<512, 256, SMEM_BYTES, stream>>>(inp, ln_f_g, ln_f_b, qk, qbuf,
                                                  A_part, psum_part, xsum_part,
                                                  it == 0 ? 1 : 0);
    s3_update<<<32, 256, S3_BYTES, stream>>>(A_part, psum_part, xsum_part,
                                             WihB, WhhB, WkB, WvT, W1T, W2T, WqT,
                                             bv, b_ih, b_hh, ln_ff_g, ln_ff_b,
                                             b1, b2, ln_s_g, ln_s_b, bq, bk,
                                             slots_cur, qk, qbuf, out);
  }
}